// Round 5
// baseline (593.872 us; speedup 1.0000x reference)
//
#include <hip/hip_runtime.h>
#include <hip/hip_bf16.h>

#define PP 32000
#define DD 128
#define BBATCH 4096

typedef __bf16 bf16x8 __attribute__((ext_vector_type(8)));
typedef float f32x4 __attribute__((ext_vector_type(4)));
typedef unsigned short ushort8 __attribute__((ext_vector_type(8)));

// RNE float -> bf16 (inputs are finite; no NaN handling needed)
__device__ __forceinline__ unsigned short f2bf(float f) {
    unsigned u = __float_as_uint(f);
    u += 0x7FFFu + ((u >> 16) & 1u);
    return (unsigned short)(u >> 16);
}

// ---------------------------------------------------------------------------
// Fragment-major operand layout (verified passing, rounds 2/4):
// For mfma_f32_16x16x32_bf16, lane l needs  A[m=l&15][k=(l>>4)*8+j], j=0..7.
// Both operands pre-tiled as [row16][ks][lane][8]: a wave's fragment load is
// base + lane*16B -> ONE coalesced 1024B instruction.
// flat elem index: ((row16*4 + ks)*64 + l)*8 + j
//   with row = row16*16 + (l&15),  k = ks*32 + (l>>4)*8 + j
// ---------------------------------------------------------------------------

__global__ void prep_hidden_kernel(const int* __restrict__ x,
                                   const float* __restrict__ W,
                                   unsigned short* __restrict__ Hb) {
    const int b = (blockIdx.x << 1) + (threadIdx.x >> 7);
    const int d = threadIdx.x & 127;
    const int i0 = x[2 * b];
    const int i1 = x[2 * b + 1];
    float h = W[(size_t)d * PP + i0] + W[(size_t)d * PP + i1];
    h = h > 0.0f ? h : 0.0f;
    const int st = ((b >> 4) << 2) | (d >> 5);             // b16*4 + ks
    const int l  = (((d & 31) >> 3) << 4) | (b & 15);      // lane
    Hb[(st << 9) + (l << 3) + (d & 7)] = f2bf(h);
}

__global__ void prep_v_kernel(const float* __restrict__ V,
                              unsigned short* __restrict__ Vb) {
    const int t  = blockIdx.x * 256 + threadIdx.x;   // 512000 chunks of 16B
    const int l  = t & 63;
    const int st = t >> 6;
    const int ks  = st & 3;
    const int p16 = st >> 2;
    const int p  = (p16 << 4) | (l & 15);
    const int k0 = (ks << 5) | ((l >> 4) << 3);
    const float4 v0 = *reinterpret_cast<const float4*>(V + (size_t)p * DD + k0);
    const float4 v1 = *reinterpret_cast<const float4*>(V + (size_t)p * DD + k0 + 4);
    ushort8 o;
    o[0] = f2bf(v0.x); o[1] = f2bf(v0.y); o[2] = f2bf(v0.z); o[3] = f2bf(v0.w);
    o[4] = f2bf(v1.x); o[5] = f2bf(v1.y); o[6] = f2bf(v1.z); o[7] = f2bf(v1.w);
    *reinterpret_cast<ushort8*>(Vb + (size_t)t * 8) = o;
}

// out[b][p] = sum_k Hb[b][k] * Vb[p][k]
// Block = 4 waves at the same 64-b tile (BT), spanning 256 p (wave w owns
// p-tile PT*4+w). MFMA roles/fragment layouts + LDS-transposed epilogue are
// byte-identical to the verified round-4 kernel.
//
// ONLY change this round: block->tile mapping. PT is now the FAST axis among
// concurrently-resident blocks, so in-flight stores cover ~all 125 p-columns
// (every HBM channel) instead of one 1KB column stripe at 128KB power-of-2
// row stride (which aliases onto a few channels and caps write BW).
//   g = bid>>3 (consecutive g ~ concurrent), PT = g % 125  -> channel spread
//   BT = (g/125)*8 + (bid&7): blocks on one XCD (bid%8 fixed under round-robin
//   dispatch) see only 8 BTs -> 128KB of Hb L2-resident; Vb streams from LLC.
__global__ void gemm_kernel(const unsigned short* __restrict__ Vb,
                            const unsigned short* __restrict__ Hb,
                            float* __restrict__ out) {
    __shared__ f32x4 lds4[32 * 64];   // 32 rows x 64 slots x 16B = 32 KB

    const int g  = blockIdx.x >> 3;                    // 0..999
    const int PT = g % 125;                            // 256-wide p block (fast)
    const int BT = (g / 125) * 8 + (blockIdx.x & 7);   // 0..63 : 64-wide b block
    const int w    = threadIdx.x >> 6;   // wave 0..3 -> p-subtile
    const int lane = threadIdx.x & 63;
    const int col = lane & 15;
    const int kq  = lane >> 4;

    const int pt = (PT << 2) + w;  // global 64-p tile
    const int b0 = BT << 6;
    const int P0 = PT << 8;

    const bf16x8* Abase = reinterpret_cast<const bf16x8*>(Vb) + (pt << 10) + lane;
    const bf16x8* Bbase = reinterpret_cast<const bf16x8*>(Hb) + (BT << 10) + lane;

    f32x4 acc[4][4];
    const f32x4 zero = {0.0f, 0.0f, 0.0f, 0.0f};
    #pragma unroll
    for (int i = 0; i < 4; ++i)
        #pragma unroll
        for (int j = 0; j < 4; ++j)
            acc[i][j] = zero;

    #pragma unroll
    for (int ks = 0; ks < 4; ++ks) {
        bf16x8 a[4], bb[4];
        #pragma unroll
        for (int i = 0; i < 4; ++i)
            a[i] = Abase[((i << 2) + ks) << 6];
        #pragma unroll
        for (int j = 0; j < 4; ++j)
            bb[j] = Bbase[((j << 2) + ks) << 6];
        #pragma unroll
        for (int i = 0; i < 4; ++i)
            #pragma unroll
            for (int j = 0; j < 4; ++j)
                acc[i][j] = __builtin_amdgcn_mfma_f32_16x16x32_bf16(
                    a[i], bb[j], acc[i][j], 0, 0, 0);
    }

    // -------- LDS-transposed epilogue, 2 phases of 32 b-rows --------
    // acc[i][j] lane layout (verified): value (i,j,reg r) is
    //   b = b0 + j*16 + col ,  p = pt*64 + i*16 + kq*4 + r
    // Phase ph covers j in {2ph, 2ph+1} i.e. local rows br = (j2*16+col).
    // Slot (16B) index within a 256-p row: s = w*16 + i*4 + kq (0..63).
    #pragma unroll
    for (int ph = 0; ph < 2; ++ph) {
        if (ph) __syncthreads();   // phase-0 readers done before overwrite
        #pragma unroll
        for (int j2 = 0; j2 < 2; ++j2) {
            const int j = (ph << 1) + j2;
            const int br = (j2 << 4) + col;            // 0..31
            #pragma unroll
            for (int i = 0; i < 4; ++i) {
                const int s = (w << 4) + (i << 2) + kq;
                lds4[(br << 6) + (s ^ br)] = acc[i][j];
            }
        }
        __syncthreads();
        // readback: 8 rows per wave; lane l takes logical slot l of the row
        #pragma unroll
        for (int r = 0; r < 8; ++r) {
            const int br = (w << 3) + r;
            const f32x4 vv = lds4[(br << 6) + (lane ^ br)];
            float* dst = out + (size_t)(b0 + (ph << 5) + br) * PP + P0 + (lane << 2);
            __builtin_nontemporal_store(vv, reinterpret_cast<f32x4*>(dst));
        }
    }
}

extern "C" void kernel_launch(void* const* d_in, const int* in_sizes, int n_in,
                              void* d_out, int out_size, void* d_ws, size_t ws_size,
                              hipStream_t stream) {
    const int*   x = (const int*)d_in[0];
    const float* W = (const float*)d_in[1];
    const float* V = (const float*)d_in[2];
    float* out = (float*)d_out;

    // workspace: Hb_tiled [4096*128] bf16 (1 MB), then Vb_tiled [32000*128] bf16 (8 MB)
    unsigned short* Hb = (unsigned short*)d_ws;
    unsigned short* Vb = Hb + (size_t)BBATCH * DD;

    prep_hidden_kernel<<<BBATCH / 2, 256, 0, stream>>>(x, W, Hb);
    prep_v_kernel<<<(PP * DD) / (8 * 256), 256, 0, stream>>>(V, Vb);
    // 125 p-blocks (256 wide) x 64 b-blocks = 8000 blocks x 4 waves
    gemm_kernel<<<8000, 256, 0, stream>>>(Vb, Hb, out);
}